// Round 3
// baseline (2613.272 us; speedup 1.0000x reference)
//
#include <hip/hip_runtime.h>

typedef _Float16 h8 __attribute__((ext_vector_type(8)));
typedef float v4f __attribute__((ext_vector_type(4)));
typedef unsigned long long ull;

#define B_  256
#define T_  512
#define I_  64
#define H_  512

// workspace layout (bytes)
#define OFF_W16   0                                   // [2048][512] f16
#define OFF_WIH   (OFF_W16 + 2048*512*2)              // [2048][64]  f16
#define OFF_BIAS  (OFF_WIH + 2048*64*2)               // [2048]      f32 (b_ih+b_hh)
#define OFF_X16   (OFF_BIAS + 2048*4)                 // [512][256][64] f16 (transposed)
#define OFF_HPK   (OFF_X16 + 512*256*64*2)            // [2][8][256][32] ull tagged packs (1MB)
// pack = { lo dword: 2 f16 h-values (cols 2p, 2p+1), hi dword: step tag }
// index (ull): buf*65536 + bg*8192 + pack*32 + row

__device__ __forceinline__ float sigf(float x) {
    float e = __builtin_amdgcn_exp2f(-1.442695041f * x);
    return __builtin_amdgcn_rcpf(1.f + e);
}
__device__ __forceinline__ float tanhf_(float x) {
    float e = __builtin_amdgcn_exp2f(2.885390082f * x);  // exp(2x)
    return 1.f - 2.f * __builtin_amdgcn_rcpf(e + 1.f);
}

union P2 { _Float16 f[2]; unsigned u; };

__global__ void prep_w(const float* __restrict__ Wih, const float* __restrict__ Whh,
                       const float* __restrict__ bih, const float* __restrict__ bhh,
                       _Float16* __restrict__ W16, _Float16* __restrict__ Wih16,
                       float* __restrict__ bias, ull* __restrict__ hpk) {
    int idx = blockIdx.x * 256 + threadIdx.x;          // grid covers 2048*512
    W16[idx] = (_Float16)Whh[idx];
    if (idx < 2048 * 64)  Wih16[idx] = (_Float16)Wih[idx];
    if (idx < 2048)       bias[idx] = bih[idx] + bhh[idx];
    // h0: zero values, tag 0, visible at the IF$ coherence point
    if (idx < 65536)
        __hip_atomic_store(hpk + idx, 0ull, __ATOMIC_RELAXED, __HIP_MEMORY_SCOPE_AGENT);
}

__global__ void prep_x(const float* __restrict__ x, _Float16* __restrict__ x16) {
    int idx = blockIdx.x * 256 + threadIdx.x;          // grid covers 512*256*64
    int t = idx >> 14;                                  // / (256*64)
    int rem = idx & 16383;
    int b = rem >> 6;
    int i = rem & 63;
    x16[idx] = (_Float16)x[((size_t)b * T_ + t) * I_ + i];
}

// 128 wgs: 8 batch-groups x 16 col-groups; wg = 32 batch rows x 32 h-cols.
// Wave w = (m = w&1, gate-pair gp = (w>>1)*2): 1 A m-tile serves 4 B-tiles
// -> A-fragment LDS volume halves vs wave-per-gate. bfrag = 4x18 h8 = 288 VGPR.
__launch_bounds__(256, 1)
__global__ void lstm_k(const _Float16* __restrict__ W16, const _Float16* __restrict__ Wih16,
                       const float* __restrict__ bias, const _Float16* __restrict__ x16,
                       ull* __restrict__ hpk) {
    __shared__ _Float16 Als[18][32][36];  // 41472 B; stride 36 halves = 18 dwords (2-way max, b64 ops)
    __shared__ float    Sg[128][36];      // 18432 B; [gatecol][row], 16B-aligned rows for f32x4

    const int tid  = threadIdx.x;
    const int lane = tid & 63;
    const int wave = tid >> 6;
    const int bg = blockIdx.x & 7;        // same bg -> same XCD under %8 round robin (perf only)
    const int cg = blockIdx.x >> 3;       // 0..15
    const int B0 = bg * 32;
    const int J0 = cg * 32;
    const int m  = wave & 1;
    const int gp = (wave >> 1) * 2;       // gates gp, gp+1
    const int r  = lane & 15;
    const int q  = lane >> 4;
    const int m16 = m * 16;
    const int q8  = q * 8;

    // --- hoist weight B-fragments: tile t = gi*2+ct ---
    h8 bf[4][18];
    float biasv[4];
#pragma unroll
    for (int gi = 0; gi < 2; ++gi)
#pragma unroll
    for (int ct = 0; ct < 2; ++ct) {
        const int t = gi * 2 + ct;
        const int wrow = (gp + gi) * H_ + J0 + ct * 16 + r;
#pragma unroll
        for (int kk = 0; kk < 16; ++kk)
            bf[t][kk] = *(const h8*)(W16 + (size_t)wrow * H_ + kk * 32 + q8);
#pragma unroll
        for (int kk = 16; kk < 18; ++kk)
            bf[t][kk] = *(const h8*)(Wih16 + (size_t)wrow * I_ + (kk - 16) * 32 + q8);
        biasv[t] = bias[wrow];
    }

    // consumer ownership: (row crow, chunks cch & cch+8), 16 packs each
    const int crow = tid & 31;
    const int cch  = tid >> 5;
    // phase-C ownership: (row er, cols ec..ec+3); c in VGPRs
    const int er = tid & 31;
    const int ec = (tid >> 5) * 4;
    float c[4] = {0.f, 0.f, 0.f, 0.f};
    // x staging
    const int xrow = tid >> 3, xs8 = tid & 7;

    ull* hbase = hpk + bg * 8192;

    for (int s = 0; s < T_; ++s) {
        // ---- phase A: poll tagged packs (tag == s) straight from IF$ ----
        {
            const ull* src = hbase + (size_t)(s & 1) * 65536;
            const int pb0 = cch * 16;
            const int pb1 = (cch + 8) * 16;
            ull v[32];
#pragma unroll
            for (int j = 0; j < 16; ++j)
                v[j] = __hip_atomic_load(src + (pb0 + j) * 32 + crow,
                                         __ATOMIC_RELAXED, __HIP_MEMORY_SCOPE_AGENT);
#pragma unroll
            for (int j = 0; j < 16; ++j)
                v[16 + j] = __hip_atomic_load(src + (pb1 + j) * 32 + crow,
                                              __ATOMIC_RELAXED, __HIP_MEMORY_SCOPE_AGENT);
            // x load overlaps the poll window
            h8 xv = *(const h8*)(x16 + ((size_t)s * B_ + B0 + xrow) * I_ + xs8 * 8);

            const unsigned tg = (unsigned)s;
            for (int guard = 0; guard < (1 << 18); ++guard) {
                bool all = true;
#pragma unroll
                for (int j = 0; j < 32; ++j) {
                    if ((unsigned)(v[j] >> 32) != tg) {
                        all = false;
                        const int p = (j < 16) ? (pb0 + j) : (pb1 + j - 16);
                        v[j] = __hip_atomic_load(src + p * 32 + crow,
                                                 __ATOMIC_RELAXED, __HIP_MEMORY_SCOPE_AGENT);
                    }
                }
                if (all) break;
            }
            // unpack: lo dwords are exactly consecutive half-pairs
#pragma unroll
            for (int j = 0; j < 8; ++j) {
                ull w0 = (ull)(unsigned)v[2*j] | ((ull)(unsigned)v[2*j+1] << 32);
                *(ull*)&Als[cch][crow][j * 4] = w0;
            }
#pragma unroll
            for (int j = 0; j < 8; ++j) {
                ull w1 = (ull)(unsigned)v[16+2*j] | ((ull)(unsigned)v[16+2*j+1] << 32);
                *(ull*)&Als[cch + 8][crow][j * 4] = w1;
            }
            union { h8 v; ull u[2]; } xa; xa.v = xv;
            *(ull*)&Als[16 + (xs8 >> 2)][xrow][(xs8 & 3) * 8]     = xa.u[0];
            *(ull*)&Als[16 + (xs8 >> 2)][xrow][(xs8 & 3) * 8 + 4] = xa.u[1];
        }
        __syncthreads();   // also orders: all C(s-1) Sg-reads done before B(s) Sg-writes

        // ---- phase B: 18 chunks x (1 A-read, 4 MFMA) ----
        v4f acc[4] = {{0,0,0,0},{0,0,0,0},{0,0,0,0},{0,0,0,0}};
#pragma unroll
        for (int kk = 0; kk < 18; ++kk) {
            union { h8 v; ull u[2]; } a;
            a.u[0] = *(const ull*)&Als[kk][m16 + r][q8];
            a.u[1] = *(const ull*)&Als[kk][m16 + r][q8 + 4];
            acc[0] = __builtin_amdgcn_mfma_f32_16x16x32_f16(a.v, bf[0][kk], acc[0], 0, 0, 0);
            acc[1] = __builtin_amdgcn_mfma_f32_16x16x32_f16(a.v, bf[1][kk], acc[1], 0, 0, 0);
            acc[2] = __builtin_amdgcn_mfma_f32_16x16x32_f16(a.v, bf[2][kk], acc[2], 0, 0, 0);
            acc[3] = __builtin_amdgcn_mfma_f32_16x16x32_f16(a.v, bf[3][kk], acc[3], 0, 0, 0);
        }
        // C/D: col=lane&15 (gatecol), row=q*4+reg (batch within m-tile)
#pragma unroll
        for (int gi = 0; gi < 2; ++gi)
#pragma unroll
        for (int ct = 0; ct < 2; ++ct) {
            const int t = gi * 2 + ct;
            v4f vv = acc[t] + biasv[t];
            *(v4f*)&Sg[(gp + gi) * 32 + ct * 16 + r][m16 + q * 4] = vv;
        }
        __syncthreads();

        // ---- phase C: LSTM cell + tagged-pack publish (no barrier needed) ----
        {
            ull* dst = hbase + (size_t)((s + 1) & 1) * 65536;
            const int pc = cg * 16 + (ec >> 1);   // first pack index for (ec, ec+1)
            const ull tagbits = ((ull)(unsigned)(s + 1)) << 32;
            P2 p0, p1;
#pragma unroll
            for (int j = 0; j < 4; ++j) {
                float iv = sigf  (Sg[      ec + j][er]);
                float fv = sigf  (Sg[ 32 + ec + j][er]);
                float gv = tanhf_(Sg[ 64 + ec + j][er]);
                float ov = sigf  (Sg[ 96 + ec + j][er]);
                c[j] = fv * c[j] + iv * gv;
                float hv = ov * tanhf_(c[j]);
                if (j < 2) p0.f[j] = (_Float16)hv; else p1.f[j - 2] = (_Float16)hv;
            }
            __hip_atomic_store(dst + (pc + 0) * 32 + er, (ull)p0.u | tagbits,
                               __ATOMIC_RELAXED, __HIP_MEMORY_SCOPE_AGENT);
            __hip_atomic_store(dst + (pc + 1) * 32 + er, (ull)p1.u | tagbits,
                               __ATOMIC_RELAXED, __HIP_MEMORY_SCOPE_AGENT);
        }
        // no barrier: next phase A polls tags; Als/Sg hazards covered by the 2 syncs
    }
}

__global__ void fc_k(const ull* __restrict__ hpk, const float* __restrict__ Wfc,
                     const float* __restrict__ bfc, float* __restrict__ out) {
    int b = blockIdx.x;
    int lane = threadIdx.x;   // 64 threads
    const ull* src = hpk + (size_t)(b >> 5) * 8192 + (b & 31);  // buffer 0 (tag 512)
    float sum = 0.f;
#pragma unroll
    for (int u = 0; u < 4; ++u) {
        int p = lane * 4 + u;
        P2 pk; pk.u = (unsigned)src[p * 32];
        sum += (float)pk.f[0] * Wfc[2 * p] + (float)pk.f[1] * Wfc[2 * p + 1];
    }
    for (int off = 32; off; off >>= 1) sum += __shfl_down(sum, off);
    if (lane == 0) out[b] = sum + bfc[0];
}

extern "C" void kernel_launch(void* const* d_in, const int* in_sizes, int n_in,
                              void* d_out, int out_size, void* d_ws, size_t ws_size,
                              hipStream_t stream) {
    (void)in_sizes; (void)n_in; (void)out_size; (void)ws_size;
    const float* x   = (const float*)d_in[0];
    const float* Wih = (const float*)d_in[1];
    const float* Whh = (const float*)d_in[2];
    const float* bih = (const float*)d_in[3];
    const float* bhh = (const float*)d_in[4];
    const float* Wfc = (const float*)d_in[5];
    const float* bfc = (const float*)d_in[6];
    float* out = (float*)d_out;

    char* ws = (char*)d_ws;
    _Float16* W16   = (_Float16*)(ws + OFF_W16);
    _Float16* Wih16 = (_Float16*)(ws + OFF_WIH);
    float*    biasf = (float*)(ws + OFF_BIAS);
    _Float16* x16   = (_Float16*)(ws + OFF_X16);
    ull*      hpk   = (ull*)(ws + OFF_HPK);

    hipLaunchKernelGGL(prep_w, dim3((2048 * 512) / 256), dim3(256), 0, stream,
                       Wih, Whh, bih, bhh, W16, Wih16, biasf, hpk);
    hipLaunchKernelGGL(prep_x, dim3((512 * 256 * 64) / 256), dim3(256), 0, stream, x, x16);
    hipLaunchKernelGGL(lstm_k, dim3(128), dim3(256), 0, stream,
                       W16, Wih16, biasf, x16, hpk);
    // T=512 even: final h (tag 512) sits in buffer 0
    hipLaunchKernelGGL(fc_k, dim3(256), dim3(64), 0, stream, hpk, Wfc, bfc, out);
}

// Round 4
// 2029.573 us; speedup vs baseline: 1.2876x; 1.2876x over previous
//
#include <hip/hip_runtime.h>

typedef _Float16 h8 __attribute__((ext_vector_type(8)));
typedef float v4f __attribute__((ext_vector_type(4)));
typedef unsigned long long ull;

#define B_  256
#define T_  512
#define I_  64
#define H_  512

// workspace layout (bytes)
#define OFF_W16   0                                   // [2048][512] f16
#define OFF_WIH   (OFF_W16 + 2048*512*2)              // [2048][64]  f16
#define OFF_BIAS  (OFF_WIH + 2048*64*2)               // [2048]      f32 (b_ih+b_hh)
#define OFF_X16   (OFF_BIAS + 2048*4)                 // [512][256][64] f16 (transposed)
#define OFF_HPK   (OFF_X16 + 512*256*64*2)            // [2][8][128][32] ull packs (512KB)
// pack = 4 consecutive f16 h-values; bit0 (LSB of f[0] mantissa) = generation parity.
// index (ull): buf*32768 + bg*4096 + pack*32 + row   (pack covers h-cols 4p..4p+3)

__device__ __forceinline__ float sigf(float x) {
    float e = __builtin_amdgcn_exp2f(-1.442695041f * x);
    return __builtin_amdgcn_rcpf(1.f + e);
}
__device__ __forceinline__ float tanhf_(float x) {
    float e = __builtin_amdgcn_exp2f(2.885390082f * x);  // exp(2x)
    return 1.f - 2.f * __builtin_amdgcn_rcpf(e + 1.f);
}

union P4 { _Float16 f[4]; ull u; };

// opaque pin: value becomes asm-defined -> cannot be rematerialized from its load,
// regalloc must keep it in VGPRs across the whole step loop.
#define PIN8(x) asm volatile("" : "+v"(x))

__global__ void prep_w(const float* __restrict__ Wih, const float* __restrict__ Whh,
                       const float* __restrict__ bih, const float* __restrict__ bhh,
                       _Float16* __restrict__ W16, _Float16* __restrict__ Wih16,
                       float* __restrict__ bias, ull* __restrict__ hpk) {
    int idx = blockIdx.x * 256 + threadIdx.x;          // grid covers 2048*512
    W16[idx] = (_Float16)Whh[idx];
    if (idx < 2048 * 64)  Wih16[idx] = (_Float16)Wih[idx];
    if (idx < 2048)       bias[idx] = bih[idx] + bhh[idx];
    // buf0 = h(0) zeros, parity 0 (valid for s=0). buf1 = parity 1 (INVALID for
    // s=1 which expects 0) so 0xAA poison / stale can never be falsely accepted.
    if (idx < 65536)
        __hip_atomic_store(hpk + idx, (idx < 32768) ? 0ull : 1ull,
                           __ATOMIC_RELAXED, __HIP_MEMORY_SCOPE_AGENT);
}

__global__ void prep_x(const float* __restrict__ x, _Float16* __restrict__ x16) {
    int idx = blockIdx.x * 256 + threadIdx.x;          // grid covers 512*256*64
    int t = idx >> 14;
    int rem = idx & 16383;
    int b = rem >> 6;
    int i = rem & 63;
    x16[idx] = (_Float16)x[((size_t)b * T_ + t) * I_ + i];
}

// 64 wgs x 512 thr: 8 batch-groups x 8 col-groups. wg = 32 rows x 64 h-cols
// (= 256 gate-cols = 16 MFMA col-tiles). Wave w: gate g=w&3, tile-half th=w>>2
// -> 2 B-tiles/wave, bfrag[2][18] = 144 VGPR, PINNED.
__launch_bounds__(512, 2)
__global__ void lstm_k(const _Float16* __restrict__ W16, const _Float16* __restrict__ Wih16,
                       const float* __restrict__ bias, const _Float16* __restrict__ x16,
                       ull* __restrict__ hpk) {
    __shared__ _Float16 Als[18][32][36];  // 41472 B; stride 36 halves (conflict-verified R3)
    __shared__ float    Sg[256][36];      // 36864 B; [gatecol][row], v4f-aligned rows

    const int tid  = threadIdx.x;
    const int lane = tid & 63;
    const int wave = tid >> 6;            // 0..7
    const int bg = blockIdx.x & 7;
    const int cg = blockIdx.x >> 3;       // 0..7
    const int B0 = bg * 32;
    const int J0 = cg * 64;
    const int g  = wave & 3;              // gate
    const int th = wave >> 2;             // tile half: col-tiles {2th, 2th+1}
    const int r  = lane & 15;
    const int q  = lane >> 4;
    const int q8 = q * 8;

    // --- weight B-fragments, loaded once, PINNED in VGPRs ---
    h8 bf[2][18];
    float biasv[2];
#pragma unroll
    for (int ct = 0; ct < 2; ++ct) {
        const int wrow = g * H_ + J0 + (th * 2 + ct) * 16 + r;
#pragma unroll
        for (int kk = 0; kk < 16; ++kk) {
            bf[ct][kk] = *(const h8*)(W16 + (size_t)wrow * H_ + kk * 32 + q8);
            PIN8(bf[ct][kk]);
        }
#pragma unroll
        for (int kk = 16; kk < 18; ++kk) {
            bf[ct][kk] = *(const h8*)(Wih16 + (size_t)wrow * I_ + (kk - 16) * 32 + q8);
            PIN8(bf[ct][kk]);
        }
        biasv[ct] = bias[wrow];
    }

    // consumer ownership: chunk pb, row; 8 packs each (full K coverage)
    const int row = tid & 31;
    const int pb  = tid >> 5;             // 0..15
    // x staging: thread -> (xrow, 4 cols)
    const int xrow = tid >> 4, xc4 = tid & 15;
    // phase-C ownership: (row er, cols ec..ec+3); c in VGPRs
    const int er = tid & 31;
    const int ec = (tid >> 5) * 4;        // 0..60
    float c[4] = {0.f, 0.f, 0.f, 0.f};

    const ull* rbase = hpk + bg * 4096;
    ull*       wbase = hpk + bg * 4096;

    for (int s = 0; s < T_; ++s) {
        // ---- phase A: 8 pack loads (IF$), parity poll, LDS stage ----
        {
            const ull* src = rbase + (size_t)(s & 1) * 32768;
            ull v[8];
#pragma unroll
            for (int j = 0; j < 8; ++j)
                v[j] = __hip_atomic_load(src + (pb * 8 + j) * 32 + row,
                                         __ATOMIC_RELAXED, __HIP_MEMORY_SCOPE_AGENT);
            // x load overlaps the poll window
            ull xv = *(const ull*)(x16 + ((size_t)s * B_ + B0 + xrow) * I_ + xc4 * 4);

            const ull expg = (ull)((s >> 1) & 1);
            for (int guard = 0; guard < (1 << 18); ++guard) {
                bool all = true;
#pragma unroll
                for (int j = 0; j < 8; ++j) {
                    if ((v[j] & 1ull) != expg) {
                        all = false;
                        v[j] = __hip_atomic_load(src + (pb * 8 + j) * 32 + row,
                                                 __ATOMIC_RELAXED, __HIP_MEMORY_SCOPE_AGENT);
                    }
                }
                if (all) break;
            }
#pragma unroll
            for (int j = 0; j < 8; ++j)
                *(ull*)&Als[pb][row][j * 4] = v[j];
            *(ull*)&Als[16 + (xc4 >> 3)][xrow][(xc4 & 7) * 4] = xv;
        }
        __syncthreads();   // Als ready; also orders C(s-1) Sg-reads before B(s) Sg-writes

        // ---- phase B: 18 chunks x (2 A b64-pair reads, 4 MFMA) ----
        v4f acc[2][2] = {{{0,0,0,0},{0,0,0,0}},{{0,0,0,0},{0,0,0,0}}};
#pragma unroll
        for (int kk = 0; kk < 18; ++kk) {
            union { h8 v; ull u[2]; } a0, a1;
            a0.u[0] = *(const ull*)&Als[kk][r][q8];
            a0.u[1] = *(const ull*)&Als[kk][r][q8 + 4];
            a1.u[0] = *(const ull*)&Als[kk][16 + r][q8];
            a1.u[1] = *(const ull*)&Als[kk][16 + r][q8 + 4];
            acc[0][0] = __builtin_amdgcn_mfma_f32_16x16x32_f16(a0.v, bf[0][kk], acc[0][0], 0, 0, 0);
            acc[0][1] = __builtin_amdgcn_mfma_f32_16x16x32_f16(a1.v, bf[0][kk], acc[0][1], 0, 0, 0);
            acc[1][0] = __builtin_amdgcn_mfma_f32_16x16x32_f16(a0.v, bf[1][kk], acc[1][0], 0, 0, 0);
            acc[1][1] = __builtin_amdgcn_mfma_f32_16x16x32_f16(a1.v, bf[1][kk], acc[1][1], 0, 0, 0);
        }
        // C/D: col=lane&15 (gatecol), row=q*4+reg (batch in m-half) [m89-verified]
#pragma unroll
        for (int ct = 0; ct < 2; ++ct) {
            const int gcol = g * 64 + (th * 2 + ct) * 16 + r;
#pragma unroll
            for (int m = 0; m < 2; ++m) {
                v4f vv = acc[ct][m] + biasv[ct];
                *(v4f*)&Sg[gcol][m * 16 + q * 4] = vv;
            }
        }
        __syncthreads();   // Sg ready; also orders B(s) Als-reads before A(s+1) writes

        // ---- phase C: LSTM cell + parity-tagged pack publish (no barrier) ----
        {
            ull* dst = wbase + (size_t)((s + 1) & 1) * 32768;
            const ull gen = (ull)(((s + 1) >> 1) & 1);
            P4 pk;
#pragma unroll
            for (int j = 0; j < 4; ++j) {
                float iv = sigf  (Sg[      ec + j][er]);
                float fv = sigf  (Sg[ 64 + ec + j][er]);
                float gv = tanhf_(Sg[128 + ec + j][er]);
                float ov = sigf  (Sg[192 + ec + j][er]);
                c[j] = fv * c[j] + iv * gv;
                pk.f[j] = (_Float16)(ov * tanhf_(c[j]));
            }
            pk.u = (pk.u & ~1ull) | gen;   // parity: costs 1 ulp on f[0]
            __hip_atomic_store(dst + ((size_t)cg * 16 + (ec >> 2)) * 32 + er, pk.u,
                               __ATOMIC_RELAXED, __HIP_MEMORY_SCOPE_AGENT);
        }
        // no end-of-step barrier: availability = parity poll; overwrite safety
        // follows from mutual consumption (reaching C(s) requires having read
        // every peer's C(s-1) packs, which requires peers passed A(s-1)).
    }
}

__global__ void fc_k(const ull* __restrict__ hpk, const float* __restrict__ Wfc,
                     const float* __restrict__ bfc, float* __restrict__ out) {
    int b = blockIdx.x;
    int lane = threadIdx.x;   // 64 threads
    // final h in buf0 (T=512 even); written via agent stores -> read agent-scope
    const ull* src = hpk + (size_t)(b >> 5) * 4096 + (b & 31);
    float sum = 0.f;
#pragma unroll
    for (int u = 0; u < 2; ++u) {
        int p = lane * 2 + u;
        P4 pk;
        pk.u = __hip_atomic_load(src + (size_t)p * 32,
                                 __ATOMIC_RELAXED, __HIP_MEMORY_SCOPE_AGENT);
#pragma unroll
        for (int j = 0; j < 4; ++j) sum += (float)pk.f[j] * Wfc[4 * p + j];
    }
    for (int off = 32; off; off >>= 1) sum += __shfl_down(sum, off);
    if (lane == 0) out[b] = sum + bfc[0];
}

extern "C" void kernel_launch(void* const* d_in, const int* in_sizes, int n_in,
                              void* d_out, int out_size, void* d_ws, size_t ws_size,
                              hipStream_t stream) {
    (void)in_sizes; (void)n_in; (void)out_size; (void)ws_size;
    const float* x   = (const float*)d_in[0];
    const float* Wih = (const float*)d_in[1];
    const float* Whh = (const float*)d_in[2];
    const float* bih = (const float*)d_in[3];
    const float* bhh = (const float*)d_in[4];
    const float* Wfc = (const float*)d_in[5];
    const float* bfc = (const float*)d_in[6];
    float* out = (float*)d_out;

    char* ws = (char*)d_ws;
    _Float16* W16   = (_Float16*)(ws + OFF_W16);
    _Float16* Wih16 = (_Float16*)(ws + OFF_WIH);
    float*    biasf = (float*)(ws + OFF_BIAS);
    _Float16* x16   = (_Float16*)(ws + OFF_X16);
    ull*      hpk   = (ull*)(ws + OFF_HPK);

    hipLaunchKernelGGL(prep_w, dim3((2048 * 512) / 256), dim3(256), 0, stream,
                       Wih, Whh, bih, bhh, W16, Wih16, biasf, hpk);
    hipLaunchKernelGGL(prep_x, dim3((512 * 256 * 64) / 256), dim3(256), 0, stream, x, x16);
    hipLaunchKernelGGL(lstm_k, dim3(64), dim3(512), 0, stream,
                       W16, Wih16, biasf, x16, hpk);
    hipLaunchKernelGGL(fc_k, dim3(256), dim3(64), 0, stream, hpk, Wfc, bfc, out);
}

// Round 5
// 1855.906 us; speedup vs baseline: 1.4081x; 1.0936x over previous
//
#include <hip/hip_runtime.h>

typedef _Float16 h8 __attribute__((ext_vector_type(8)));
typedef float v4f __attribute__((ext_vector_type(4)));
typedef unsigned long long ull;

#define B_  256
#define T_  512
#define I_  64
#define H_  512

// workspace layout (bytes)
#define OFF_W16   0                                   // [2048][512] f16
#define OFF_WIH   (OFF_W16 + 2048*512*2)              // [2048][64]  f16
#define OFF_BIAS  (OFF_WIH + 2048*64*2)               // [2048]      f32 (b_ih+b_hh)
#define OFF_X16   (OFF_BIAS + 2048*4)                 // [512][256][64] f16 (transposed)
#define OFF_HPK   (OFF_X16 + 512*256*64*2)            // [2][8][128][32] ull packs (512KB)
// pack = 4 consecutive f16 h-values; bit0 (LSB of f[0] mantissa) = generation parity.
// index (ull): buf*32768 + bg*4096 + pack*32 + row   (pack covers h-cols 4p..4p+3)

__device__ __forceinline__ float sigf(float x) {
    float e = __builtin_amdgcn_exp2f(-1.442695041f * x);
    return __builtin_amdgcn_rcpf(1.f + e);
}
__device__ __forceinline__ float tanhf_(float x) {
    float e = __builtin_amdgcn_exp2f(2.885390082f * x);  // exp(2x)
    return 1.f - 2.f * __builtin_amdgcn_rcpf(e + 1.f);
}

union P4 { _Float16 f[4]; ull u; };

// Pin into ACC registers: separate allocation class, MFMA reads B from AGPR
// natively on gfx950 (unified file). "+a" makes the value asm-defined ->
// non-rematerializable, and AGPRs don't compete with the arch-VGPR budget
// the scheduler tries to minimize.
#define PINA(x) asm volatile("" : "+a"(x))

__global__ void prep_w(const float* __restrict__ Wih, const float* __restrict__ Whh,
                       const float* __restrict__ bih, const float* __restrict__ bhh,
                       _Float16* __restrict__ W16, _Float16* __restrict__ Wih16,
                       float* __restrict__ bias, ull* __restrict__ hpk) {
    int idx = blockIdx.x * 256 + threadIdx.x;          // grid covers 2048*512
    W16[idx] = (_Float16)Whh[idx];
    if (idx < 2048 * 64)  Wih16[idx] = (_Float16)Wih[idx];
    if (idx < 2048)       bias[idx] = bih[idx] + bhh[idx];
    // buf0 = h(0) zeros, parity 0 (valid for s=0). buf1 = parity 1 (invalid for
    // s=1 which expects 0) so 0xAA poison / stale can never be falsely accepted.
    if (idx < 65536)
        __hip_atomic_store(hpk + idx, (idx < 32768) ? 0ull : 1ull,
                           __ATOMIC_RELAXED, __HIP_MEMORY_SCOPE_AGENT);
}

__global__ void prep_x(const float* __restrict__ x, _Float16* __restrict__ x16) {
    int idx = blockIdx.x * 256 + threadIdx.x;          // grid covers 512*256*64
    int t = idx >> 14;
    int rem = idx & 16383;
    int b = rem >> 6;
    int i = rem & 63;
    x16[idx] = (_Float16)x[((size_t)b * T_ + t) * I_ + i];
}

// 128 wgs x 256 thr: 8 batch-groups x 16 col-groups; wg = 32 rows x 32 h-cols
// (=128 gate-cols). Wave w = gate g: 2 col-tiles -> bf[2][18] = 144 AGPRs,
// pinned. 128 wgs -> 1 wg/CU on 128 CUs, 1 wave/SIMD of MFMA.
__launch_bounds__(256, 2)
__global__ void lstm_k(const _Float16* __restrict__ W16, const _Float16* __restrict__ Wih16,
                       const float* __restrict__ bias, const _Float16* __restrict__ x16,
                       ull* __restrict__ hpk) {
    __shared__ _Float16 Als[18][32][36];  // 41472 B; stride-36 halves (conflict-verified)
    __shared__ float    Sg[128][36];      // 18432 B; [gatecol][row], v4f-aligned rows

    const int tid  = threadIdx.x;
    const int lane = tid & 63;
    const int g    = tid >> 6;            // wave == gate 0..3
    const int bg = blockIdx.x & 7;
    const int cg = blockIdx.x >> 3;       // 0..15
    const int B0 = bg * 32;
    const int J0 = cg * 32;
    const int r  = lane & 15;
    const int q  = lane >> 4;
    const int q8 = q * 8;

    // --- weight B-fragments, loaded once, pinned in AGPRs ---
    h8 bf[2][18];
    float biasv[2];
#pragma unroll
    for (int ct = 0; ct < 2; ++ct) {
        const int wrow = g * H_ + J0 + ct * 16 + r;    // gate-col index
#pragma unroll
        for (int kk = 0; kk < 16; ++kk) {
            bf[ct][kk] = *(const h8*)(W16 + (size_t)wrow * H_ + kk * 32 + q8);
            PINA(bf[ct][kk]);
        }
#pragma unroll
        for (int kk = 16; kk < 18; ++kk) {
            bf[ct][kk] = *(const h8*)(Wih16 + (size_t)wrow * I_ + (kk - 16) * 32 + q8);
            PINA(bf[ct][kk]);
        }
        biasv[ct] = bias[wrow];
    }

    // consumer ownership: row = tid&31, 16 packs starting at (tid>>5)*16
    const int row = tid & 31;
    const int pb  = tid >> 5;             // 0..7
    // x staging: thread -> (xrow, 8 cols)
    const int xrow = tid >> 3, xs8 = tid & 7;
    // phase-C ownership: (row er, cols ec..ec+3); c in VGPRs
    const int er = tid & 31;
    const int ec = (tid >> 5) * 4;        // 0..28
    float c[4] = {0.f, 0.f, 0.f, 0.f};

    ull* hbase = hpk + bg * 4096;

    for (int s = 0; s < T_; ++s) {
        // ---- phase A: 16 pack loads (IF$), parity poll, LDS stage ----
        {
            const ull* src = hbase + (size_t)(s & 1) * 32768;
            ull v[16];
#pragma unroll
            for (int j = 0; j < 16; ++j)
                v[j] = __hip_atomic_load(src + (pb * 16 + j) * 32 + row,
                                         __ATOMIC_RELAXED, __HIP_MEMORY_SCOPE_AGENT);
            // x load overlaps the poll window
            h8 xv = *(const h8*)(x16 + ((size_t)s * B_ + B0 + xrow) * I_ + xs8 * 8);

            const ull expg = (ull)((s >> 1) & 1);
            for (int guard = 0; guard < (1 << 18); ++guard) {
                bool all = true;
#pragma unroll
                for (int j = 0; j < 16; ++j) {
                    if ((v[j] & 1ull) != expg) {
                        all = false;
                        v[j] = __hip_atomic_load(src + (pb * 16 + j) * 32 + row,
                                                 __ATOMIC_RELAXED, __HIP_MEMORY_SCOPE_AGENT);
                    }
                }
                if (all) break;
                if (guard >= 4) __builtin_amdgcn_s_sleep(1);  // backoff after early rounds
            }
            // pack p = pb*16+j -> chunk p>>3, within-chunk col (p&7)*4
#pragma unroll
            for (int j = 0; j < 16; ++j)
                *(ull*)&Als[pb * 2 + (j >> 3)][row][(j & 7) * 4] = v[j];
            union { h8 v; ull u[2]; } xa; xa.v = xv;
            *(ull*)&Als[16 + (xs8 >> 2)][xrow][(xs8 & 3) * 8]     = xa.u[0];
            *(ull*)&Als[16 + (xs8 >> 2)][xrow][(xs8 & 3) * 8 + 4] = xa.u[1];
        }
        __syncthreads();   // Als ready; also orders C(s-1) Sg-reads before B(s) Sg-writes

        // ---- phase B: 18 chunks x (2 A-reads, 4 MFMA); weights from AGPRs ----
        v4f acc[2][2] = {{{0,0,0,0},{0,0,0,0}},{{0,0,0,0},{0,0,0,0}}};
#pragma unroll
        for (int kk = 0; kk < 18; ++kk) {
            union { h8 v; ull u[2]; } a0, a1;
            a0.u[0] = *(const ull*)&Als[kk][r][q8];
            a0.u[1] = *(const ull*)&Als[kk][r][q8 + 4];
            a1.u[0] = *(const ull*)&Als[kk][16 + r][q8];
            a1.u[1] = *(const ull*)&Als[kk][16 + r][q8 + 4];
            acc[0][0] = __builtin_amdgcn_mfma_f32_16x16x32_f16(a0.v, bf[0][kk], acc[0][0], 0, 0, 0);
            acc[0][1] = __builtin_amdgcn_mfma_f32_16x16x32_f16(a1.v, bf[0][kk], acc[0][1], 0, 0, 0);
            acc[1][0] = __builtin_amdgcn_mfma_f32_16x16x32_f16(a0.v, bf[1][kk], acc[1][0], 0, 0, 0);
            acc[1][1] = __builtin_amdgcn_mfma_f32_16x16x32_f16(a1.v, bf[1][kk], acc[1][1], 0, 0, 0);
        }
        // C/D: col=lane&15 (gatecol), row=q*4+reg (batch in m-half) [m89-verified]
#pragma unroll
        for (int ct = 0; ct < 2; ++ct) {
            const int gcol = g * 32 + ct * 16 + r;
#pragma unroll
            for (int m = 0; m < 2; ++m) {
                v4f vv = acc[ct][m] + biasv[ct];
                *(v4f*)&Sg[gcol][m * 16 + q * 4] = vv;
            }
        }
        __syncthreads();   // Sg ready; also orders B(s) Als-reads before A(s+1) writes

        // ---- phase C: LSTM cell + parity-tagged pack publish (no barrier) ----
        {
            ull* dst = hbase + (size_t)((s + 1) & 1) * 32768;
            const ull gen = (ull)(((s + 1) >> 1) & 1);
            P4 pk;
#pragma unroll
            for (int j = 0; j < 4; ++j) {
                float iv = sigf  (Sg[      ec + j][er]);
                float fv = sigf  (Sg[ 32 + ec + j][er]);
                float gv = tanhf_(Sg[ 64 + ec + j][er]);
                float ov = sigf  (Sg[ 96 + ec + j][er]);
                c[j] = fv * c[j] + iv * gv;
                pk.f[j] = (_Float16)(ov * tanhf_(c[j]));
            }
            pk.u = (pk.u & ~1ull) | gen;   // parity: costs 1 ulp on f[0]
            __hip_atomic_store(dst + ((size_t)cg * 8 + (ec >> 2)) * 32 + er, pk.u,
                               __ATOMIC_RELAXED, __HIP_MEMORY_SCOPE_AGENT);
        }
        // no end-of-step barrier: overwrite safety via mutual consumption
        // (reaching C(s) requires A(s) observed every peer's C(s-1) packs).
    }
}

__global__ void fc_k(const ull* __restrict__ hpk, const float* __restrict__ Wfc,
                     const float* __restrict__ bfc, float* __restrict__ out) {
    int b = blockIdx.x;
    int lane = threadIdx.x;   // 64 threads
    // final h in buf0 (T=512 even); kernel-boundary makes stores visible
    const ull* src = hpk + (size_t)(b >> 5) * 4096 + (b & 31);
    float sum = 0.f;
#pragma unroll
    for (int u = 0; u < 2; ++u) {
        int p = lane * 2 + u;
        P4 pk;
        pk.u = __hip_atomic_load(src + (size_t)p * 32,
                                 __ATOMIC_RELAXED, __HIP_MEMORY_SCOPE_AGENT);
#pragma unroll
        for (int j = 0; j < 4; ++j) sum += (float)pk.f[j] * Wfc[4 * p + j];
    }
    for (int off = 32; off; off >>= 1) sum += __shfl_down(sum, off);
    if (lane == 0) out[b] = sum + bfc[0];
}

extern "C" void kernel_launch(void* const* d_in, const int* in_sizes, int n_in,
                              void* d_out, int out_size, void* d_ws, size_t ws_size,
                              hipStream_t stream) {
    (void)in_sizes; (void)n_in; (void)out_size; (void)ws_size;
    const float* x   = (const float*)d_in[0];
    const float* Wih = (const float*)d_in[1];
    const float* Whh = (const float*)d_in[2];
    const float* bih = (const float*)d_in[3];
    const float* bhh = (const float*)d_in[4];
    const float* Wfc = (const float*)d_in[5];
    const float* bfc = (const float*)d_in[6];
    float* out = (float*)d_out;

    char* ws = (char*)d_ws;
    _Float16* W16   = (_Float16*)(ws + OFF_W16);
    _Float16* Wih16 = (_Float16*)(ws + OFF_WIH);
    float*    biasf = (float*)(ws + OFF_BIAS);
    _Float16* x16   = (_Float16*)(ws + OFF_X16);
    ull*      hpk   = (ull*)(ws + OFF_HPK);

    hipLaunchKernelGGL(prep_w, dim3((2048 * 512) / 256), dim3(256), 0, stream,
                       Wih, Whh, bih, bhh, W16, Wih16, biasf, hpk);
    hipLaunchKernelGGL(prep_x, dim3((512 * 256 * 64) / 256), dim3(256), 0, stream, x, x16);
    hipLaunchKernelGGL(lstm_k, dim3(128), dim3(256), 0, stream,
                       W16, Wih16, biasf, x16, hpk);
    hipLaunchKernelGGL(fc_k, dim3(256), dim3(64), 0, stream, hpk, Wfc, bfc, out);
}